// Round 2
// baseline (345.902 us; speedup 1.0000x reference)
//
#include <hip/hip_runtime.h>

// DeepPoly ReLU relaxation — purely elementwise, memory-bound.
// Traffic: 6 fp32 streams x 16M elems = 402.7 MB -> ~64 us floor at 6.3 TB/s.
// Timed region ~= 2 harness poison-fills (~242us, uncontrollable) + kernel.
// R4: persistent 2048-block grid-stride + next-tile prefetch = NEUTRAL
//     (kernel ~80us @ ~5.0 TB/s in both structures) -> not a pipeline-drain
//     problem; MLP already sufficient at 32 waves/CU x 6 outstanding vmem.
// R5 theory: __builtin_nontemporal_load bypasses L2 on the READ path; m13's
//     6.29 TB/s copy ceiling was measured with plain cached loads (L2 absorbs
//     and prefetches full lines). nt is right for STORES (output never re-read
//     in timed region) but plausibly throttles reads to ~8 B/cyc/CU.
// R5 change: plain loads + nt stores, same persistent prefetch structure.
// Predicted: kernel ~80 -> ~66-70us; bench dur_us 322 -> ~306-312.
//     If neutral: 3R+3W mixed plateau is structural -> ROOFLINE next round.

typedef float f32x4 __attribute__((ext_vector_type(4)));

__device__ __forceinline__ void relax4(f32x4 xv, f32x4 lv, f32x4 hv,
                                       f32x4& xr, f32x4& lr, f32x4& hr) {
#pragma unroll
    for (int j = 0; j < 4; ++j) {
        float xx = xv[j], l = lv[j], h = hv[j];
        bool crossing = (l < 0.0f) && (h > 0.0f);
        bool inactive = (h <= 0.0f);
        // crossing => h>0, l<0 => h-l > 0. Speculative rcp; selected away otherwise.
        float inv = __builtin_amdgcn_rcpf(h - l);
        float ub_slope = crossing ? (h * inv) : (inactive ? 0.0f : 1.0f);
        float ub_int   = crossing ? (-(l * h) * inv) : 0.0f;
        float lamda    = (l * l > h * h) ? 0.0f : 1.0f;
        float lb_slope = crossing ? lamda : (inactive ? 0.0f : 1.0f);
        float xo = fmaxf(xx, 0.0f);
        float ho = ub_slope * h + ub_int;
        float lo = lb_slope * l;
        xr[j] = xo;
        lr[j] = lo;
        hr[j] = ho;
    }
}

__global__ __launch_bounds__(256) void abstract_relu_kernel(
        const f32x4* __restrict__ x,
        const f32x4* __restrict__ low,
        const f32x4* __restrict__ high,
        f32x4* __restrict__ x_out,
        f32x4* __restrict__ low_out,
        f32x4* __restrict__ high_out,
        int stride,     // gridDim.x * blockDim.x, in f32x4 units
        int iters) {    // n4 / stride (exact; n = 2^24)
    int i = blockIdx.x * blockDim.x + threadIdx.x;

    // Preload tile 0 — PLAIN cached loads (R5: keep the read path in L2).
    f32x4 cx = x[i];
    f32x4 cl = low[i];
    f32x4 ch = high[i];

    for (int it = 1; it < iters; ++it) {
        int ni = i + stride;
        // Next tile's loads issue before the current tile's stores.
        f32x4 nx = x[ni];
        f32x4 nl = low[ni];
        f32x4 nh = high[ni];

        f32x4 xr, lr, hr;
        relax4(cx, cl, ch, xr, lr, hr);
        __builtin_nontemporal_store(xr, &x_out[i]);
        __builtin_nontemporal_store(lr, &low_out[i]);
        __builtin_nontemporal_store(hr, &high_out[i]);

        cx = nx; cl = nl; ch = nh; i = ni;
    }

    // Drain last tile.
    f32x4 xr, lr, hr;
    relax4(cx, cl, ch, xr, lr, hr);
    __builtin_nontemporal_store(xr, &x_out[i]);
    __builtin_nontemporal_store(lr, &low_out[i]);
    __builtin_nontemporal_store(hr, &high_out[i]);
}

extern "C" void kernel_launch(void* const* d_in, const int* in_sizes, int n_in,
                              void* d_out, int out_size, void* d_ws, size_t ws_size,
                              hipStream_t stream) {
    const int n = in_sizes[0];          // 16777216 = 2^24
    const int n4 = n / 4;               // 4,194,304 float4s

    const f32x4* x    = (const f32x4*)d_in[0];
    const f32x4* low  = (const f32x4*)d_in[1];
    const f32x4* high = (const f32x4*)d_in[2];

    float* out = (float*)d_out;         // [relu(x) | low_out | high_out]
    f32x4* x_out    = (f32x4*)(out);
    f32x4* low_out  = (f32x4*)(out + (size_t)n);
    f32x4* high_out = (f32x4*)(out + (size_t)2 * n);

    const int block  = 256;
    const int grid   = 2048;            // 8 blocks/CU -> 32 waves/CU
    const int stride = grid * block;    // 524288 f32x4 per sweep
    const int iters  = n4 / stride;     // 8 (exact for n = 2^24)

    abstract_relu_kernel<<<grid, block, 0, stream>>>(
        x, low, high, x_out, low_out, high_out, stride, iters);
}

// Round 3
// 328.611 us; speedup vs baseline: 1.0526x; 1.0526x over previous
//
#include <hip/hip_runtime.h>

// DeepPoly ReLU relaxation — purely elementwise, memory-bound.
// Traffic: 6 fp32 streams x 16M elems = 402.7 MB -> ~64 us floor at 6.3 TB/s.
// Timed region = ~224 us fixed harness poison-fills + kernel.
// Cache-flag matrix (kernel-only time, backed out of bench deltas + rocprof):
//   (nt ld, nt st)    = ~98 us  (4.1 TB/s)   R0/R1
//   (plain ld, nt st) = ~122 us (regression) R2 — FETCH dropped to 98 MB (L3
//       served half the reads) yet SLOWER -> cache-allocating READ path is
//       fabric-limited, not HBM-limited. nt loads are right.
// R6 theory: nt stores bypass L2 and interleave fine-grained writes with the
//     read stream at the memory controllers -> R/W turnaround on every switch.
//     Plain stores write-allocate in L2 (write-back) -> HBM writes arrive as
//     batched eviction bursts (how m13's 1R:1W copy sustains 6.29 TB/s, and
//     the write-only fill 6.6). L3 pollution is irrelevant: reads bypass.
// R6 change: nt loads + PLAIN stores. Structure unchanged.
// Predicted: kernel ~98 -> 75-85 us; bench 346 -> ~300-310.

typedef float f32x4 __attribute__((ext_vector_type(4)));

__device__ __forceinline__ void relax4(f32x4 xv, f32x4 lv, f32x4 hv,
                                       f32x4& xr, f32x4& lr, f32x4& hr) {
#pragma unroll
    for (int j = 0; j < 4; ++j) {
        float xx = xv[j], l = lv[j], h = hv[j];
        bool crossing = (l < 0.0f) && (h > 0.0f);
        bool inactive = (h <= 0.0f);
        // crossing => h>0, l<0 => h-l > 0. Speculative rcp; selected away otherwise.
        float inv = __builtin_amdgcn_rcpf(h - l);
        float ub_slope = crossing ? (h * inv) : (inactive ? 0.0f : 1.0f);
        float ub_int   = crossing ? (-(l * h) * inv) : 0.0f;
        float lamda    = (l * l > h * h) ? 0.0f : 1.0f;
        float lb_slope = crossing ? lamda : (inactive ? 0.0f : 1.0f);
        float xo = fmaxf(xx, 0.0f);
        float ho = ub_slope * h + ub_int;
        float lo = lb_slope * l;
        xr[j] = xo;
        lr[j] = lo;
        hr[j] = ho;
    }
}

__global__ __launch_bounds__(256) void abstract_relu_kernel(
        const f32x4* __restrict__ x,
        const f32x4* __restrict__ low,
        const f32x4* __restrict__ high,
        f32x4* __restrict__ x_out,
        f32x4* __restrict__ low_out,
        f32x4* __restrict__ high_out,
        int stride,     // gridDim.x * blockDim.x, in f32x4 units
        int iters) {    // n4 / stride (exact; n = 2^24)
    int i = blockIdx.x * blockDim.x + threadIdx.x;

    // Preload tile 0 — nt loads (R2 proved cache-allocating reads are slower).
    f32x4 cx = __builtin_nontemporal_load(&x[i]);
    f32x4 cl = __builtin_nontemporal_load(&low[i]);
    f32x4 ch = __builtin_nontemporal_load(&high[i]);

    for (int it = 1; it < iters; ++it) {
        int ni = i + stride;
        // Next tile's loads issue before the current tile's stores.
        f32x4 nx = __builtin_nontemporal_load(&x[ni]);
        f32x4 nl = __builtin_nontemporal_load(&low[ni]);
        f32x4 nh = __builtin_nontemporal_load(&high[ni]);

        f32x4 xr, lr, hr;
        relax4(cx, cl, ch, xr, lr, hr);
        // PLAIN stores: write-allocate in L2, let write-back batch HBM writes.
        x_out[i]    = xr;
        low_out[i]  = lr;
        high_out[i] = hr;

        cx = nx; cl = nl; ch = nh; i = ni;
    }

    // Drain last tile.
    f32x4 xr, lr, hr;
    relax4(cx, cl, ch, xr, lr, hr);
    x_out[i]    = xr;
    low_out[i]  = lr;
    high_out[i] = hr;
}

extern "C" void kernel_launch(void* const* d_in, const int* in_sizes, int n_in,
                              void* d_out, int out_size, void* d_ws, size_t ws_size,
                              hipStream_t stream) {
    const int n = in_sizes[0];          // 16777216 = 2^24
    const int n4 = n / 4;               // 4,194,304 float4s

    const f32x4* x    = (const f32x4*)d_in[0];
    const f32x4* low  = (const f32x4*)d_in[1];
    const f32x4* high = (const f32x4*)d_in[2];

    float* out = (float*)d_out;         // [relu(x) | low_out | high_out]
    f32x4* x_out    = (f32x4*)(out);
    f32x4* low_out  = (f32x4*)(out + (size_t)n);
    f32x4* high_out = (f32x4*)(out + (size_t)2 * n);

    const int block  = 256;
    const int grid   = 2048;            // 8 blocks/CU -> 32 waves/CU
    const int stride = grid * block;    // 524288 f32x4 per sweep
    const int iters  = n4 / stride;     // 8 (exact for n = 2^24)

    abstract_relu_kernel<<<grid, block, 0, stream>>>(
        x, low, high, x_out, low_out, high_out, stride, iters);
}

// Round 4
// 326.527 us; speedup vs baseline: 1.0593x; 1.0064x over previous
//
#include <hip/hip_runtime.h>

// DeepPoly ReLU relaxation — purely elementwise, memory-bound.
// Traffic: 6 fp32 streams x 16M elems = 402.7 MB -> ~64 us floor at 6.3 TB/s.
// Timed region = ~224 us fixed harness poison-fills + kernel (model: bench =
// 223.9 + kernel, calibrated from R2's directly-profiled 122 us dispatch).
// Cache-flag matrix (kernel-only):
//   (nt,nt) = ~98 us (4.1 TB/s)  BEST   R0/R1
//   (plain ld, nt st) = 122 us — L3 served half the reads yet SLOWER
//   (nt ld, plain st) = ~105 us — L2 write-back path slower than nt stream
//   -> any cache-allocating endpoint throttles this mix; flag axis exhausted.
// Structure axis exhausted too: one-shot 2-chunk == persistent prefetch.
// R7 theory: remaining delta vs references is STREAMS PER THREAD.
//   fill(1 stream)=6.75 TB/s, copy(2 streams)=6.29, ours(6 lockstep streams,
//   pow2-aligned bases -> identical low addr bits -> same channel/bank
//   sequence for all 6 simultaneously) = 4.1. Split the op into its two
//   independent factors: x->x_out (2-stream relu copy, 1024 blocks) and
//   (low,high)->(low_out,high_out) (4 streams, 2048 blocks). Per-thread
//   bytes balanced (16x32B vs 8x64B). Wave-uniform block branch.
// Predicted: kernel ~98 -> 78-85 us; bench 322 -> ~302-309.
//   If neutral: all levers exhausted -> structural plateau, ROOFLINE.

typedef float f32x4 __attribute__((ext_vector_type(4)));

__global__ __launch_bounds__(256) void abstract_relu_kernel(
        const f32x4* __restrict__ x,
        const f32x4* __restrict__ low,
        const f32x4* __restrict__ high,
        f32x4* __restrict__ x_out,
        f32x4* __restrict__ low_out,
        f32x4* __restrict__ high_out) {
    const int bid = blockIdx.x;

    if (bid < 1024) {
        // ---- Group A: relu copy, 2 streams. 1024 blocks x 256 thr, 16 iters.
        int i = bid * 256 + threadIdx.x;
        const int stride = 1024 * 256;          // 262144 f32x4
#pragma unroll
        for (int it = 0; it < 16; ++it) {
            f32x4 xv = __builtin_nontemporal_load(&x[i]);
            f32x4 xr;
            xr[0] = fmaxf(xv[0], 0.0f);
            xr[1] = fmaxf(xv[1], 0.0f);
            xr[2] = fmaxf(xv[2], 0.0f);
            xr[3] = fmaxf(xv[3], 0.0f);
            __builtin_nontemporal_store(xr, &x_out[i]);
            i += stride;
        }
    } else {
        // ---- Group B: bounds pair, 4 streams. 2048 blocks x 256 thr, 8 iters.
        int i = (bid - 1024) * 256 + threadIdx.x;
        const int stride = 2048 * 256;          // 524288 f32x4
#pragma unroll
        for (int it = 0; it < 8; ++it) {
            f32x4 lv = __builtin_nontemporal_load(&low[i]);
            f32x4 hv = __builtin_nontemporal_load(&high[i]);
            f32x4 lr, hr;
#pragma unroll
            for (int j = 0; j < 4; ++j) {
                float l = lv[j], h = hv[j];
                bool crossing = (l < 0.0f) && (h > 0.0f);
                bool inactive = (h <= 0.0f);
                // crossing => h>0, l<0 => h-l>0. Speculative rcp, selected away.
                float inv = __builtin_amdgcn_rcpf(h - l);
                float ub_slope = crossing ? (h * inv) : (inactive ? 0.0f : 1.0f);
                float ub_int   = crossing ? (-(l * h) * inv) : 0.0f;
                float lamda    = (l * l > h * h) ? 0.0f : 1.0f;
                float lb_slope = crossing ? lamda : (inactive ? 0.0f : 1.0f);
                lr[j] = lb_slope * l;
                hr[j] = ub_slope * h + ub_int;
            }
            __builtin_nontemporal_store(lr, &low_out[i]);
            __builtin_nontemporal_store(hr, &high_out[i]);
            i += stride;
        }
    }
}

extern "C" void kernel_launch(void* const* d_in, const int* in_sizes, int n_in,
                              void* d_out, int out_size, void* d_ws, size_t ws_size,
                              hipStream_t stream) {
    const int n = in_sizes[0];          // 16777216 = 2^24

    const f32x4* x    = (const f32x4*)d_in[0];
    const f32x4* low  = (const f32x4*)d_in[1];
    const f32x4* high = (const f32x4*)d_in[2];

    float* out = (float*)d_out;         // [relu(x) | low_out | high_out]
    f32x4* x_out    = (f32x4*)(out);
    f32x4* low_out  = (f32x4*)(out + (size_t)n);
    f32x4* high_out = (f32x4*)(out + (size_t)2 * n);

    const int block = 256;
    const int grid  = 3072;             // 1024 relu-copy + 2048 bounds blocks
    abstract_relu_kernel<<<grid, block, 0, stream>>>(
        x, low, high, x_out, low_out, high_out);
}

// Round 5
// 324.187 us; speedup vs baseline: 1.0670x; 1.0072x over previous
//
#include <hip/hip_runtime.h>

// DeepPoly ReLU relaxation — purely elementwise, memory-bound.
// Traffic: 6 fp32 streams x 16M elems = 402.7 MB -> ~64 us kernel floor at
// 6.3 TB/s. Timed region = ~224 us fixed harness poison-fills + kernel
// (model: bench = 223.9 + kernel, calibrated from R2's profiled dispatch).
//
// Session journal (kernel-only times, backed out of bench via the model):
//   R0/R1 (nt ld, nt st), one-shot 8192 blk:        ~98.5 us  (4.1 TB/s) BEST
//   R1    persistent 2048-blk prefetch pipeline:    ~99.9 us  neutral
//   R2    (plain ld, nt st): FETCH dropped to 98 MB (L3 served half the
//         reads) yet SLOWER (122.4 us) -> cache-allocating read path is
//         fabric-limited, not HBM-limited.
//   R3    (nt ld, plain st): 105.1 us -> L2 write-back path slower than nt.
//   R7    split-stream (1024 relu-copy blk + 2048 bounds blk): 102.6 us ->
//         per-thread stream count / lockstep channels not the limiter.
// Conclusion: ~4.1 TB/s is the structural plateau for this 3R:3W nt mix on
// gfx950 — three different structures and three cache-flag combos converge.
// This file = the best configuration (R0), restored.

typedef float f32x4 __attribute__((ext_vector_type(4)));

__device__ __forceinline__ void relax1(float x, float l, float h,
                                       float& xo, float& lo, float& ho) {
    bool crossing = (l < 0.0f) && (h > 0.0f);
    bool inactive = (h <= 0.0f);
    // crossing => h>0, l<0 => h-l > 0. Speculative rcp; selected away otherwise.
    float inv = __builtin_amdgcn_rcpf(h - l);
    float ub_slope = crossing ? (h * inv) : (inactive ? 0.0f : 1.0f);
    float ub_int   = crossing ? (-(l * h) * inv) : 0.0f;
    float lamda    = (l * l > h * h) ? 0.0f : 1.0f;
    float lb_slope = crossing ? lamda : (inactive ? 0.0f : 1.0f);
    xo = fmaxf(x, 0.0f);
    ho = ub_slope * h + ub_int;
    lo = lb_slope * l;
}

__device__ __forceinline__ void relax4(f32x4 xv, f32x4 lv, f32x4 hv,
                                       f32x4& xr, f32x4& lr, f32x4& hr) {
#pragma unroll
    for (int j = 0; j < 4; ++j) {
        float xo, lo, ho;
        relax1(xv[j], lv[j], hv[j], xo, lo, ho);
        xr[j] = xo;
        lr[j] = lo;
        hr[j] = ho;
    }
}

__global__ __launch_bounds__(256) void abstract_relu_kernel(
        const f32x4* __restrict__ x,
        const f32x4* __restrict__ low,
        const f32x4* __restrict__ high,
        f32x4* __restrict__ x_out,
        f32x4* __restrict__ low_out,
        f32x4* __restrict__ high_out) {
    // Each block handles 512 float4s: lanes cover [base, base+256) and
    // [base+256, base+512) — both halves fully coalesced.
    int base = blockIdx.x * 512 + threadIdx.x;
    int i0 = base;
    int i1 = base + 256;

    f32x4 xv0 = __builtin_nontemporal_load(&x[i0]);
    f32x4 lv0 = __builtin_nontemporal_load(&low[i0]);
    f32x4 hv0 = __builtin_nontemporal_load(&high[i0]);
    f32x4 xv1 = __builtin_nontemporal_load(&x[i1]);
    f32x4 lv1 = __builtin_nontemporal_load(&low[i1]);
    f32x4 hv1 = __builtin_nontemporal_load(&high[i1]);

    f32x4 xr0, lr0, hr0, xr1, lr1, hr1;
    relax4(xv0, lv0, hv0, xr0, lr0, hr0);
    relax4(xv1, lv1, hv1, xr1, lr1, hr1);

    __builtin_nontemporal_store(xr0, &x_out[i0]);
    __builtin_nontemporal_store(lr0, &low_out[i0]);
    __builtin_nontemporal_store(hr0, &high_out[i0]);
    __builtin_nontemporal_store(xr1, &x_out[i1]);
    __builtin_nontemporal_store(lr1, &low_out[i1]);
    __builtin_nontemporal_store(hr1, &high_out[i1]);
}

extern "C" void kernel_launch(void* const* d_in, const int* in_sizes, int n_in,
                              void* d_out, int out_size, void* d_ws, size_t ws_size,
                              hipStream_t stream) {
    const int n = in_sizes[0];          // 16777216 = 2^24, divisible by 2048
    const int n4 = n / 4;               // float4 count

    const f32x4* x    = (const f32x4*)d_in[0];
    const f32x4* low  = (const f32x4*)d_in[1];
    const f32x4* high = (const f32x4*)d_in[2];

    float* out = (float*)d_out;         // [relu(x) | low_out | high_out]
    f32x4* x_out    = (f32x4*)(out);
    f32x4* low_out  = (f32x4*)(out + (size_t)n);
    f32x4* high_out = (f32x4*)(out + (size_t)2 * n);

    const int block = 256;
    const int grid  = n4 / 512;         // 8192 blocks, 512 float4s per block
    abstract_relu_kernel<<<grid, block, 0, stream>>>(
        x, low, high, x_out, low_out, high_out);
}